// Round 2
// baseline (3051.392 us; speedup 1.0000x reference)
//
#include <hip/hip_runtime.h>
#include <math.h>

typedef unsigned short u16;
typedef unsigned int   u32;
typedef long long      i64;
typedef __attribute__((ext_vector_type(8))) __bf16 bf16x8;
typedef __attribute__((ext_vector_type(4))) float  f32x4;
typedef __attribute__((ext_vector_type(8))) u16    u16x8;

#define LN_EPS 1e-12f

__device__ __forceinline__ float b2f(u16 u){ union {u32 i; float f;} v; v.i = ((u32)u)<<16; return v.f; }
__device__ __forceinline__ u16 f2b(float f){ union {float f; u32 i;} v; v.f = f; u32 r = v.i + 0x7FFFu + ((v.i>>16)&1u); return (u16)(r>>16); }

__device__ __forceinline__ void gl2lds16(const u16* g, u16* l) {
  __builtin_amdgcn_global_load_lds((const __attribute__((address_space(1))) void*)g,
                                   (__attribute__((address_space(3))) void*)l, 16, 0, 0);
}

// ---------------------------------------------------------------- GEMM (B^T)
// C[m][n] = sum_k A[m][k] * Bt[n][k] (+f32 bias, +gelu). A/Bt bf16; C bf16 or f32.
struct GemmArgs {
  const u16* A; const u16* Bt; void* C;
  const float* bias0; const float* bias1; const float* bias2;
  i64 sAb, sAh, sBb, sBh, sCb, sCh;
  int lda, ldb, ldc, M, N, K, bias_seg, act, hdiv, cf32;
};

template<int BM, int BN, int WM, int WN>
__global__ __launch_bounds__(WM*WN*64)
void gemm_bt(GemmArgs g) {
  constexpr int NT = WM*WN*64;
  constexpr int RA = (BM*32)/(NT*8);
  constexpr int RB = (BN*32)/(NT*8);
  __shared__ u16 As[BM*32];
  __shared__ u16 Bs[BN*32];
  const int tid  = threadIdx.x;
  const int wave = tid >> 6, lane = tid & 63;
  const int wm = wave / WN, wn = wave % WN;
  const int z  = blockIdx.z;
  const int zb = z / g.hdiv, zh = z % g.hdiv;
  const u16* A  = g.A  + (i64)zb*g.sAb + (i64)zh*g.sAh + (i64)blockIdx.x*BM*g.lda;
  const u16* Bt = g.Bt + (i64)zb*g.sBb + (i64)zh*g.sBh;
  const int n0 = blockIdx.y * BN;
  const int lrow = lane & 15, quad = lane >> 4;

  f32x4 acc[4][4];
  #pragma unroll
  for (int i=0;i<4;i++)
    #pragma unroll
    for (int j=0;j<4;j++) acc[i][j] = (f32x4){0.f,0.f,0.f,0.f};

  for (int k0 = 0; k0 < g.K; k0 += 32) {
    #pragma unroll
    for (int r = 0; r < RA; r++) {
      int gran = r*NT + tid;
      int row = gran >> 2;
      int col = (gran & 3) << 3;
      const u16* src = A + (i64)row*g.lda + k0 + col;
      int base = (r*NT + (wave<<6)) << 3;       // wave-uniform LDS base (elements)
      gl2lds16(src, &As[base]);
    }
    #pragma unroll
    for (int r = 0; r < RB; r++) {
      int gran = r*NT + tid;
      int row = gran >> 2;
      int nrow = n0 + row; if (nrow >= g.N) nrow = g.N - 1;   // clamp (stores guarded)
      int col = (gran & 3) << 3;
      const u16* src = Bt + (i64)nrow*g.ldb + k0 + col;
      int base = (r*NT + (wave<<6)) << 3;
      gl2lds16(src, &Bs[base]);
    }
    __syncthreads();
    bf16x8 af[4], bfv[4];
    #pragma unroll
    for (int i=0;i<4;i++) af[i]  = *(const bf16x8*)&As[(((wm<<6)+(i<<4)+lrow)<<5) + (quad<<3)];
    #pragma unroll
    for (int j=0;j<4;j++) bfv[j] = *(const bf16x8*)&Bs[(((wn<<6)+(j<<4)+lrow)<<5) + (quad<<3)];
    #pragma unroll
    for (int i=0;i<4;i++)
      #pragma unroll
      for (int j=0;j<4;j++)
        acc[i][j] = __builtin_amdgcn_mfma_f32_16x16x32_bf16(af[i], bfv[j], acc[i][j], 0,0,0);
    __syncthreads();
  }

  const i64 rowbase = (i64)blockIdx.x*BM + (wm<<6);
  u16*   Cb = (u16*)g.C   + (i64)zb*g.sCb + (i64)zh*g.sCh;
  float* Cf = (float*)g.C + (i64)zb*g.sCb + (i64)zh*g.sCh;
  #pragma unroll
  for (int i=0;i<4;i++) {
    #pragma unroll
    for (int j=0;j<4;j++) {
      int col = n0 + (wn<<6) + (j<<4) + lrow;
      if (col < g.N) {
        float bias = 0.f;
        if (g.bias0) {
          int seg = col / g.bias_seg;
          const float* bp = (seg==0) ? g.bias0 : ((seg==1) ? g.bias1 : g.bias2);
          bias = bp[col - seg*g.bias_seg];
        }
        #pragma unroll
        for (int r=0;r<4;r++) {
          i64 row = rowbase + (i<<4) + (quad<<2) + r;
          float v = acc[i][j][r] + bias;
          if (g.act == 1) v = 0.5f*v*(1.0f + erff(v*0.70710678118654752f));
          if (g.cf32) Cf[row*(i64)g.ldc + col] = v;
          else        Cb[row*(i64)g.ldc + col] = f2b(v);
        }
      }
    }
  }
}

// ---------------------------------------------------------------- softmax
// S: (48, 512, 512) bf16 raw scores; scale, optional causal mask, softmax in place.
__global__ __launch_bounds__(256) void softmax_kernel(u16* S, int causal) {
  int rowg = blockIdx.x*4 + (threadIdx.x >> 6);
  int lane = threadIdx.x & 63;
  int q = rowg & 511;
  u16* Srow = S + (i64)rowg*512;
  u16x8 raw = *(const u16x8*)&Srow[lane*8];
  float v[8];
  #pragma unroll
  for (int j=0;j<8;j++) {
    int k = lane*8 + j;
    float x = b2f(raw[j]) * 0.125f;
    if (causal && k > q) x = -1e30f;
    v[j] = x;
  }
  float m = v[0];
  #pragma unroll
  for (int j=1;j<8;j++) m = fmaxf(m, v[j]);
  #pragma unroll
  for (int off=32; off; off>>=1) m = fmaxf(m, __shfl_xor(m, off));
  float s = 0.f;
  #pragma unroll
  for (int j=0;j<8;j++) { v[j] = __expf(v[j] - m); s += v[j]; }
  #pragma unroll
  for (int off=32; off; off>>=1) s += __shfl_xor(s, off);
  float inv = 1.0f / s;
  u16x8 o;
  #pragma unroll
  for (int j=0;j<8;j++) o[j] = f2b(v[j]*inv);
  *(u16x8*)&Srow[lane*8] = o;
}

// ---------------------------------------------------------------- LN helpers
__device__ __forceinline__ float block_reduce_sum_256(float v, float* red) {
  #pragma unroll
  for (int off=32; off; off>>=1) v += __shfl_xor(v, off);
  int wave = threadIdx.x >> 6;
  __syncthreads();
  if ((threadIdx.x & 63) == 0) red[wave] = v;
  __syncthreads();
  return red[0]+red[1]+red[2]+red[3];
}

// y = LN(base + delta)*g + b  (all f32). Writes f32 master and bf16 mirror.
__global__ __launch_bounds__(256) void resln_kernel(const float* base, const float* delta,
                                                    const float* gam, const float* bet,
                                                    float* out_f, u16* out_b) {
  __shared__ float red[4];
  i64 off = (i64)blockIdx.x * 768;
  int tid = threadIdx.x;
  float x[3];
  #pragma unroll
  for (int j=0;j<3;j++) {
    int i = tid + j*256;
    float v = delta[off+i];
    if (base) v += base[off+i];
    x[j] = v;
  }
  float s = block_reduce_sum_256(x[0]+x[1]+x[2], red);
  float mean = s * (1.0f/768.0f);
  float q = 0.f;
  #pragma unroll
  for (int j=0;j<3;j++) { float d = x[j]-mean; q += d*d; }
  q = block_reduce_sum_256(q, red);
  float r = rsqrtf(q*(1.0f/768.0f) + LN_EPS);
  #pragma unroll
  for (int j=0;j<3;j++) {
    int i = tid + j*256;
    float y = (x[j]-mean)*r*gam[i] + bet[i];
    out_f[off+i] = y;
    out_b[off+i] = f2b(y);
  }
}

// h[row] = LN(word_emb[id] + pos_emb[s] + tok_emb[0])*g + b  (f32 in, f32+bf16 out)
__global__ __launch_bounds__(256) void embed_kernel(const int* ids, const float* wemb,
    const float* pemb, const float* temb, const float* gam, const float* bet,
    float* out_f, u16* out_b) {
  __shared__ float red[4];
  int row = blockIdx.x;
  int s = row & 511;
  i64 wrow = (i64)ids[row] * 768;
  i64 off = (i64)row * 768;
  int tid = threadIdx.x;
  float x[3];
  #pragma unroll
  for (int j=0;j<3;j++) {
    int i = tid + j*256;
    x[j] = wemb[wrow+i] + pemb[(i64)s*768+i] + temb[i];
  }
  float sm = block_reduce_sum_256(x[0]+x[1]+x[2], red);
  float mean = sm * (1.0f/768.0f);
  float q = 0.f;
  #pragma unroll
  for (int j=0;j<3;j++) { float d = x[j]-mean; q += d*d; }
  q = block_reduce_sum_256(q, red);
  float r = rsqrtf(q*(1.0f/768.0f) + LN_EPS);
  #pragma unroll
  for (int j=0;j<3;j++) {
    int i = tid + j*256;
    float y = (x[j]-mean)*r*gam[i] + bet[i];
    out_f[off+i] = y;
    out_b[off+i] = f2b(y);
  }
}

// f32 -> bf16 elementwise (encoder_hidden mirror)
__global__ __launch_bounds__(256) void cvt_kernel(const float* src, u16* dst, int n) {
  int i = (blockIdx.x*256 + threadIdx.x) * 4;
  if (i + 3 < n) {
    float4 v = *(const float4*)&src[i];
    dst[i+0]=f2b(v.x); dst[i+1]=f2b(v.y); dst[i+2]=f2b(v.z); dst[i+3]=f2b(v.w);
  }
}

// ---------------------------------------------------------------- transposes
struct TransEntry { const float* src; u16* dst; int K, N, tile0; };
struct TransArgs  { TransEntry e[12]; int n; };

// dst[n][k] = bf16(src[k][n]); 64x64 tiles; K % 64 == 0; N may be ragged.
__global__ __launch_bounds__(256) void transpose_multi(TransArgs ta) {
  __shared__ u16 tile[64][72];
  int t = blockIdx.x;
  int ei = 0;
  for (int i=1;i<ta.n;i++) if (t >= ta.e[i].tile0) ei = i;
  TransEntry E = ta.e[ei];
  int lt = t - E.tile0;
  int ntn = (E.N + 63) >> 6;
  int tk = lt / ntn, tn = lt - tk*ntn;
  int tid = threadIdx.x;
  int kk = tid >> 2, c = (tid & 3) << 4;
  i64 gk = (i64)(tk*64 + kk);
  int gn0 = tn*64 + c;
  const float* srow = E.src + gk * E.N;
  if (gn0 + 16 <= E.N) {
    #pragma unroll
    for (int j=0;j<16;j++) tile[kk][c+j] = f2b(srow[gn0+j]);
  } else {
    for (int j=0;j<16;j++) tile[kk][c+j] = (gn0+j < E.N) ? f2b(srow[gn0+j]) : (u16)0;
  }
  __syncthreads();
  int nn = tid >> 2, kc = (tid & 3) << 4;
  int gn = tn*64 + nn;
  if (gn < E.N) {
    u16x8 v0, v1;
    #pragma unroll
    for (int j=0;j<8;j++) { v0[j] = tile[kc+j][nn]; v1[j] = tile[kc+8+j][nn]; }
    u16* drow = E.dst + (i64)gn*E.K + tk*64 + kc;
    *(u16x8*)&drow[0] = v0;
    *(u16x8*)&drow[8] = v1;
  }
}

// VT[bh][d][key] = qkv[b*512+key][1536 + h*64 + d]   (bf16 -> bf16)
__global__ __launch_bounds__(256) void vtrans_kernel(const u16* qkv, u16* VT) {
  __shared__ u16 tile[64][72];
  int bh = blockIdx.z; int b = bh / 12, hh = bh % 12;
  const u16* src = qkv + (i64)b*512*2304 + 1536 + hh*64;
  u16* dst = VT + (i64)bh*64*512;
  int kt = blockIdx.x;
  int tid = threadIdx.x;
  int kk = tid >> 2, c = (tid & 3) << 4;
  const u32* p = (const u32*)&src[(i64)(kt*64+kk)*2304 + c];
  #pragma unroll
  for (int j=0;j<8;j++) *(u32*)&tile[kk][c + 2*j] = p[j];
  __syncthreads();
  int dd = tid >> 2, kc = (tid & 3) << 4;
  u16x8 v0, v1;
  #pragma unroll
  for (int j=0;j<8;j++) { v0[j] = tile[kc+j][dd]; v1[j] = tile[kc+8+j][dd]; }
  u16* drow = dst + (i64)dd*512 + kt*64 + kc;
  *(u16x8*)&drow[0] = v0;
  *(u16x8*)&drow[8] = v1;
}

// ---------------------------------------------------------------- host side
static void gemm128(const u16* A, int lda, const u16* Bt, int ldb, void* C, int ldc,
                    int M, int N, int K, const float* b0, const float* b1, const float* b2,
                    int bias_seg, int act, int cf32, hipStream_t st) {
  GemmArgs g;
  g.A=A; g.Bt=Bt; g.C=C; g.bias0=b0; g.bias1=b1; g.bias2=b2;
  g.sAb=0; g.sAh=0; g.sBb=0; g.sBh=0; g.sCb=0; g.sCh=0;
  g.lda=lda; g.ldb=ldb; g.ldc=ldc; g.M=M; g.N=N; g.K=K;
  g.bias_seg=bias_seg; g.act=act; g.hdiv=1; g.cf32=cf32;
  dim3 grid(M/128, (N+127)/128, 1);
  gemm_bt<128,128,2,2><<<grid, 256, 0, st>>>(g);
}

extern "C" void kernel_launch(void* const* d_in, const int* in_sizes, int n_in,
                              void* d_out, int out_size, void* d_ws, size_t ws_size,
                              hipStream_t stream) {
  (void)in_sizes; (void)n_in; (void)out_size;
  const int*   ids  = (const int*)d_in[0];
  const float* enc  = (const float*)d_in[1];
  const float* wemb = (const float*)d_in[2];
  const float* pemb = (const float*)d_in[3];
  const float* temb = (const float*)d_in[4];
  const float* eg   = (const float*)d_in[5];
  const float* eb   = (const float*)d_in[6];
  const float* Wq=(const float*)d_in[7];  const float* bq=(const float*)d_in[8];
  const float* Wk=(const float*)d_in[9];  const float* bk=(const float*)d_in[10];
  const float* Wv=(const float*)d_in[11]; const float* bv=(const float*)d_in[12];
  const float* Wo=(const float*)d_in[13]; const float* bo=(const float*)d_in[14];
  const float* l1g=(const float*)d_in[15]; const float* l1b=(const float*)d_in[16];
  const float* cWq=(const float*)d_in[17]; const float* cbq=(const float*)d_in[18];
  const float* cWk=(const float*)d_in[19]; const float* cbk=(const float*)d_in[20];
  const float* cWv=(const float*)d_in[21]; const float* cbv=(const float*)d_in[22];
  const float* cWo=(const float*)d_in[23]; const float* cbo=(const float*)d_in[24];
  const float* l2g=(const float*)d_in[25]; const float* l2b=(const float*)d_in[26];
  const float* Wi=(const float*)d_in[27];  const float* bi=(const float*)d_in[28];
  const float* Wf=(const float*)d_in[29];  const float* bff=(const float*)d_in[30];
  const float* l3g=(const float*)d_in[31]; const float* l3b=(const float*)d_in[32];
  const float* Wt=(const float*)d_in[33];  const float* bt=(const float*)d_in[34];
  const float* lhg=(const float*)d_in[35]; const float* lhb=(const float*)d_in[36];
  const float* Wdec=(const float*)d_in[37]; const float* bdec=(const float*)d_in[38];
  float* out = (float*)d_out;

  // workspace layout (u16 units)
  u16* ws     = (u16*)d_ws;
  u16* WT     = ws;                          // 24,030,720 u16 (reused per layer / head)
  u16* h_bf   = WT + 24030720;               // 1,572,864 u16
  float* h_f  = (float*)(h_bf + 1572864);    // 1,572,864 f32
  float* h2_f = h_f + 1572864;               // 1,572,864 f32
  u16* qkv    = (u16*)(h2_f + 1572864);      // 4,718,592 u16
  u16* ctx    = qkv + 4718592;               // 1,572,864 u16
  u16* VT     = ctx + 1572864;               // 1,572,864 u16
  u16* enc_bf = VT + 1572864;                // 1,572,864 u16
  u16* Smat   = enc_bf + 1572864;            // 12,582,912 u16 (attention only)
  u16* mid    = Smat;                        // 6,291,456 u16 (FFN only, aliases Smat)
  // total = 53,915,136 u16 = 107.8 MB
  if (ws_size < (size_t)53915136 * 2) return;

  const int DD = 589824, DF = 2359296;
  // per-layer WT sub-regions (bf16)
  u16* qkvT = WT;                 // 2304x768
  u16* woT  = WT + 1769472;       // 768x768
  u16* cqT  = WT + 2359296;       // 768x768
  u16* ckvT = WT + 2949120;       // 1536x768
  u16* cwoT = WT + 4128768;       // 768x768
  u16* wiT  = WT + 4718592;       // 3072x768
  u16* wfT  = WT + 7077888;       // 768x3072

  embed_kernel<<<2048, 256, 0, stream>>>(ids, wemb, pemb, temb, eg, eb, h_f, h_bf);
  cvt_kernel<<<1536, 256, 0, stream>>>(enc, enc_bf, 1572864);

  for (int l = 0; l < 6; l++) {
    // transpose+convert this layer's weights
    TransArgs ta; int tile = 0; int idx = 0;
    auto add = [&](const float* s, u16* d, int K, int N) {
      ta.e[idx].src=s; ta.e[idx].dst=d; ta.e[idx].K=K; ta.e[idx].N=N; ta.e[idx].tile0=tile;
      tile += (K/64)*((N+63)/64); idx++;
    };
    add(Wq +(i64)l*DD, qkvT,        768, 768);
    add(Wk +(i64)l*DD, qkvT+DD,     768, 768);
    add(Wv +(i64)l*DD, qkvT+2*DD,   768, 768);
    add(Wo +(i64)l*DD, woT,         768, 768);
    add(cWq+(i64)l*DD, cqT,         768, 768);
    add(cWk+(i64)l*DD, ckvT,        768, 768);
    add(cWv+(i64)l*DD, ckvT+DD,     768, 768);
    add(cWo+(i64)l*DD, cwoT,        768, 768);
    add(Wi +(i64)l*DF, wiT,         768, 3072);
    add(Wf +(i64)l*DF, wfT,         3072, 768);
    ta.n = idx;
    transpose_multi<<<tile, 256, 0, stream>>>(ta);

    // ---- self attention ----
    gemm128(h_bf, 768, qkvT, 768, qkv, 2304, 2048, 2304, 768,
            bq+l*768, bk+l*768, bv+l*768, 768, 0, 0, stream);
    vtrans_kernel<<<dim3(8,1,48), 256, 0, stream>>>(qkv, VT);
    {
      GemmArgs g; g.A=qkv; g.sAb=512LL*2304; g.sAh=64; g.lda=2304;
      g.Bt=qkv+768; g.sBb=512LL*2304; g.sBh=64; g.ldb=2304;
      g.C=Smat; g.sCb=12LL*262144; g.sCh=262144; g.ldc=512;
      g.M=512; g.N=512; g.K=64; g.bias0=nullptr; g.bias1=nullptr; g.bias2=nullptr;
      g.bias_seg=512; g.act=0; g.hdiv=12; g.cf32=0;
      gemm_bt<128,128,2,2><<<dim3(4,4,48), 256, 0, stream>>>(g);
    }
    softmax_kernel<<<6144, 256, 0, stream>>>(Smat, 1);
    {
      GemmArgs g; g.A=Smat; g.sAb=12LL*262144; g.sAh=262144; g.lda=512;
      g.Bt=VT; g.sBb=12LL*32768; g.sBh=32768; g.ldb=512;
      g.C=ctx; g.sCb=512LL*768; g.sCh=64; g.ldc=768;
      g.M=512; g.N=64; g.K=512; g.bias0=nullptr; g.bias1=nullptr; g.bias2=nullptr;
      g.bias_seg=64; g.act=0; g.hdiv=12; g.cf32=0;
      gemm_bt<128,64,2,1><<<dim3(4,1,48), 128, 0, stream>>>(g);
    }
    gemm128(ctx, 768, woT, 768, h2_f, 768, 2048, 768, 768,
            bo+l*768, nullptr, nullptr, 768, 0, 1, stream);
    resln_kernel<<<2048, 256, 0, stream>>>(h_f, h2_f, l1g+l*768, l1b+l*768, h_f, h_bf);

    // ---- cross attention ----
    gemm128(h_bf, 768, cqT, 768, qkv, 2304, 2048, 768, 768,
            cbq+l*768, nullptr, nullptr, 768, 0, 0, stream);
    gemm128(enc_bf, 768, ckvT, 768, qkv+768, 2304, 2048, 1536, 768,
            cbk+l*768, cbv+l*768, nullptr, 768, 0, 0, stream);
    vtrans_kernel<<<dim3(8,1,48), 256, 0, stream>>>(qkv, VT);
    {
      GemmArgs g; g.A=qkv; g.sAb=512LL*2304; g.sAh=64; g.lda=2304;
      g.Bt=qkv+768; g.sBb=512LL*2304; g.sBh=64; g.ldb=2304;
      g.C=Smat; g.sCb=12LL*262144; g.sCh=262144; g.ldc=512;
      g.M=512; g.N=512; g.K=64; g.bias0=nullptr; g.bias1=nullptr; g.bias2=nullptr;
      g.bias_seg=512; g.act=0; g.hdiv=12; g.cf32=0;
      gemm_bt<128,128,2,2><<<dim3(4,4,48), 256, 0, stream>>>(g);
    }
    softmax_kernel<<<6144, 256, 0, stream>>>(Smat, 0);
    {
      GemmArgs g; g.A=Smat; g.sAb=12LL*262144; g.sAh=262144; g.lda=512;
      g.Bt=VT; g.sBb=12LL*32768; g.sBh=32768; g.ldb=512;
      g.C=ctx; g.sCb=512LL*768; g.sCh=64; g.ldc=768;
      g.M=512; g.N=64; g.K=512; g.bias0=nullptr; g.bias1=nullptr; g.bias2=nullptr;
      g.bias_seg=64; g.act=0; g.hdiv=12; g.cf32=0;
      gemm_bt<128,64,2,1><<<dim3(4,1,48), 128, 0, stream>>>(g);
    }
    gemm128(ctx, 768, cwoT, 768, h2_f, 768, 2048, 768, 768,
            cbo+l*768, nullptr, nullptr, 768, 0, 1, stream);
    resln_kernel<<<2048, 256, 0, stream>>>(h_f, h2_f, l2g+l*768, l2b+l*768, h_f, h_bf);

    // ---- FFN ----
    gemm128(h_bf, 768, wiT, 768, mid, 3072, 2048, 3072, 768,
            bi+l*3072, nullptr, nullptr, 3072, 1, 0, stream);
    gemm128(mid, 3072, wfT, 3072, h2_f, 768, 2048, 768, 3072,
            bff+l*768, nullptr, nullptr, 768, 0, 1, stream);
    resln_kernel<<<2048, 256, 0, stream>>>(h_f, h2_f, l3g+l*768, l3b+l*768, h_f, h_bf);
  }

  // ---- MLM head ----
  u16* wtT   = WT;            // 768x768
  u16* wdecT = WT + 589824;   // 30522x768
  {
    TransArgs ta; int tile = 0; int idx = 0;
    auto add = [&](const float* s, u16* d, int K, int N) {
      ta.e[idx].src=s; ta.e[idx].dst=d; ta.e[idx].K=K; ta.e[idx].N=N; ta.e[idx].tile0=tile;
      tile += (K/64)*((N+63)/64); idx++;
    };
    add(Wt,   wtT,   768, 768);
    add(Wdec, wdecT, 768, 30522);
    ta.n = idx;
    transpose_multi<<<tile, 256, 0, stream>>>(ta);
  }
  gemm128(h_bf, 768, wtT, 768, h2_f, 768, 2048, 768, 768, bt, nullptr, nullptr, 768, 1, 1, stream);
  resln_kernel<<<2048, 256, 0, stream>>>(nullptr, h2_f, lhg, lhb, h_f, h_bf);
  gemm128(h_bf, 768, wdecT, 768, out, 30522, 2048, 30522, 768,
          bdec, nullptr, nullptr, 30522, 0, 1, stream);
}